// Round 12
// baseline (59.003 us; speedup 1.0000x reference)
//
#include <hip/hip_runtime.h>

// NIoULoss_pixel: B=8, N=8, H=W=512. One-pass fused reduction.
// R12: R11's body (thin two-phase, 16 asm-pinned loads, counted vmcnt) with
// the 3-kernel tail collapsed: per-block lane0 atomics into the 20KB padded
// ws (128 RMW/line - proven harmless regime R1/R5; R8's killer was 1024/line),
// final kernel reads ws directly. Also: per-plane-pair counted drain
// (vmcnt(4) for pp=0) overlaps mask landing with processing.
// Evidence note: rocprof VGPR_Count proven unreliable (32 reported for a
// 48-live-VGPR batch) - register-based tells retired.

constexpr int Bc  = 8;
constexpr int Nc  = 8;
constexpr int HWc = 512 * 512;
constexpr int BPI = 512;              // blocks per image (512 px per block)
constexpr int PAD = 16;               // floats per counter slot (64 B line)
constexpr float EPSc = 1e-6f;

__device__ __forceinline__ float2 gload_f2(const float* a) {
    float2 r;
    asm volatile("global_load_dwordx2 %0, %1, off" : "=v"(r) : "v"(a) : "memory");
    return r;
}
__device__ __forceinline__ int4 gload_i4(const int* a) {
    int4 r;
    asm volatile("global_load_dwordx4 %0, %1, off" : "=v"(r) : "v"(a) : "memory");
    return r;
}
#define WAITV(n_) do {                                                   \
        asm volatile("s_waitcnt vmcnt(" #n_ ")" ::: "memory");           \
        __builtin_amdgcn_sched_barrier(0);                               \
    } while (0)

__device__ __forceinline__ float wave_reduce(float v) {
#pragma unroll
    for (int off = 32; off; off >>= 1) v += __shfl_xor(v, off, 64);
    return v;
}

// 4096 blocks, 256 threads, 512 pixels/block.
__global__ __launch_bounds__(256, 4) void niou_partial(
    const float* __restrict__ pd, const float* __restrict__ gt,
    const int* __restrict__ pmask, const int* __restrict__ gmask,
    float* __restrict__ ws /* [B][40][PAD] */)
{
    __shared__ float dnL[512], poL[512], goL[512];   // unpadded: b64 W / b128 R

    const int tid  = threadIdx.x;
    const int b    = blockIdx.x >> 9;
    const int blk  = blockIdx.x & 511;
    const int base = blk * 512;

    // ---- issue 8 rgbo dwordx2 loads (oldest in queue) ----
    const float* pdB = pd + (size_t)b * 4 * HWc + base + 2 * tid;
    const float* gtB = gt + (size_t)b * 4 * HWc + base + 2 * tid;
    float2 pr[4], gr[4];
#pragma unroll
    for (int c = 0; c < 4; ++c) pr[c] = gload_f2(pdB + (size_t)c * HWc);
#pragma unroll
    for (int c = 0; c < 4; ++c) gr[c] = gload_f2(gtB + (size_t)c * HWc);

    // ---- issue 8 mask int4 loads: planes 2g,2g+1, quads q and q+64 ----
    const int g = tid >> 6, q = tid & 63;
    int4 pmv[2][2], gmv[2][2];   // [plane pp][quad qq]
#pragma unroll
    for (int pp = 0; pp < 2; ++pp) {
        const size_t pl = (size_t)(b * Nc + 2 * g + pp) * HWc + base + 4 * q;
#pragma unroll
        for (int qq = 0; qq < 2; ++qq) {
            pmv[pp][qq] = gload_i4(pmask + pl + 256 * qq);
            gmv[pp][qq] = gload_i4(gmask + pl + 256 * qq);
        }
    }

    // ---- rgbo done (8 oldest); 8 mask loads still in flight ----
    WAITV(8);
    {
        const float dx0 = pr[0].x - gr[0].x, dy0 = pr[1].x - gr[1].x, dz0 = pr[2].x - gr[2].x;
        const float dx1 = pr[0].y - gr[0].y, dy1 = pr[1].y - gr[1].y, dz1 = pr[2].y - gr[2].y;
        float2 d2, p2, g2;
        d2.x = sqrtf(dx0*dx0 + dy0*dy0 + dz0*dz0);
        d2.y = sqrtf(dx1*dx1 + dy1*dy1 + dz1*dz1);
        p2.x = rintf(pr[3].x); p2.y = rintf(pr[3].y);
        g2.x = rintf(gr[3].x); g2.y = rintf(gr[3].y);
        *reinterpret_cast<float2*>(&dnL[2 * tid]) = d2;
        *reinterpret_cast<float2*>(&poL[2 * tid]) = p2;
        *reinterpret_cast<float2*>(&goL[2 * tid]) = g2;
    }
    __syncthreads();

    // ---- LDS pixel quantities for this thread's two quads ----
    float4 dnq[2], poq[2], goq[2];
#pragma unroll
    for (int qq = 0; qq < 2; ++qq) {
        const int li = 256 * qq + 4 * q;
        dnq[qq] = *reinterpret_cast<const float4*>(&dnL[li]);
        poq[qq] = *reinterpret_cast<const float4*>(&poL[li]);
        goq[qq] = *reinterpret_cast<const float4*>(&goL[li]);
    }

    // acc[pp]: {sim_sum, inter, gt_sum, s_sum}; count via ballot
    float acc[2][4];
    int   wcnt[2];
#pragma unroll
    for (int pp = 0; pp < 2; ++pp) {
        wcnt[pp] = 0;
#pragma unroll
        for (int k = 0; k < 4; ++k) acc[pp][k] = 0.f;
    }

    // ---- counted drain: pp=0 ready at vmcnt(4), pp=1 at vmcnt(0) ----
#pragma unroll
    for (int pp = 0; pp < 2; ++pp) {
        if (pp == 0) WAITV(4); else WAITV(0);
#pragma unroll
        for (int qq = 0; qq < 2; ++qq) {
            const int pmx[4] = {pmv[pp][qq].x, pmv[pp][qq].y, pmv[pp][qq].z, pmv[pp][qq].w};
            const int gmx[4] = {gmv[pp][qq].x, gmv[pp][qq].y, gmv[pp][qq].z, gmv[pp][qq].w};
            const float dnj[4] = {dnq[qq].x, dnq[qq].y, dnq[qq].z, dnq[qq].w};
            const float poj[4] = {poq[qq].x, poq[qq].y, poq[qq].z, poq[qq].w};
            const float goj[4] = {goq[qq].x, goq[qq].y, goq[qq].z, goq[qq].w};
#pragma unroll
            for (int j = 0; j < 4; ++j) {
                const bool P = pmx[j] != 0;
                const bool G = gmx[j] != 0;
                wcnt[pp] += __popcll(__ballot(P));
                const float s = P ? poj[j] : 0.f;
                acc[pp][0] += P ? dnj[j] : 0.f;
                acc[pp][1] += G ? s      : 0.f;   // inter = (P&&G)?po:0
                acc[pp][2] += G ? goj[j] : 0.f;
                acc[pp][3] += s;                  // xor = s_sum - inter (final)
            }
        }
    }

    // ---- wave-level reduction; lane0 atomics (128 RMW/line total) ----
    const int lane = tid & 63;
#pragma unroll
    for (int pp = 0; pp < 2; ++pp) {
        const float s0 = wave_reduce(acc[pp][0]);
        const float s1 = wave_reduce(acc[pp][1]);
        const float s2 = wave_reduce(acc[pp][2]);
        const float s3 = wave_reduce(acc[pp][3]);
        if (lane == 0) {
            const int n = 2 * g + pp;
            float* wsn = ws + (size_t)(b * 40 + n * 5) * PAD;
            atomicAdd(&wsn[0 * PAD], s0);
            atomicAdd(&wsn[1 * PAD], (float)wcnt[pp]);
            atomicAdd(&wsn[2 * PAD], s1);
            atomicAdd(&wsn[3 * PAD], s2);
            atomicAdd(&wsn[4 * PAD], s3);
        }
    }
}

__global__ __launch_bounds__(64) void niou_final(
    const float* __restrict__ w0, float* __restrict__ out)
{
    const int t = threadIdx.x;   // 0..63 == b*8+n
    const float* w = w0 + (size_t)t * 5 * PAD;
    const float sim   = w[0 * PAD];
    const float cnt   = w[1 * PAD];
    const float inter = w[2 * PAD];
    const float gts   = w[3 * PAD];
    const float ssum  = w[4 * PAD];
    const float xo    = ssum - inter;            // pd_xor_sum
    const float punish = sim / (cnt + EPSc);
    const float iou    = inter / (gts + xo + EPSc);
    float term = 1.0f - iou + punish;
#pragma unroll
    for (int off = 32; off; off >>= 1) term += __shfl_xor(term, off, 64);
    if (t == 0) out[0] = term * (1.0f / 64.0f);
}

extern "C" void kernel_launch(void* const* d_in, const int* in_sizes, int n_in,
                              void* d_out, int out_size, void* d_ws, size_t ws_size,
                              hipStream_t stream) {
    const float* pd_rgbo = (const float*)d_in[0];
    const float* gt_rgbo = (const float*)d_in[1];
    const int*   pd_mask = (const int*)d_in[2];
    const int*   gt_mask = (const int*)d_in[3];
    float* out = (float*)d_out;
    float* ws  = (float*)d_ws;

    hipMemsetAsync(ws, 0, Bc * 40 * PAD * sizeof(float), stream);
    niou_partial<<<Bc * BPI, 256, 0, stream>>>(pd_rgbo, gt_rgbo, pd_mask, gt_mask, ws);
    niou_final<<<1, 64, 0, stream>>>(ws, out);
}

// Round 13
// 40.397 us; speedup vs baseline: 1.4606x; 1.4606x over previous
//
#include <hip/hip_runtime.h>

// NIoULoss_pixel: B=8, N=8, H=W=512. One-pass fused reduction.
// R13: R11's proven body + tail (38.6us; R12's atomic tail cost 45ns/same-line
// RMW x 512 = +20us -> reverted to partials+reduce). New: 2-deep software
// pipeline per block (1024 px, double-buffered LDS): iter1's 16 loads issued
// before iter0's masks are consumed; counted vmcnt drains (in-order VMEM
// retirement): WAITV(16)=mask0, WAITV(8)=rgbo1, WAITV(0)=mask1. Doubles
// compute per HBM stall (~200->400ns per ~1.2us wave lifetime) and halves
// epilogue traffic (BPI=256).

constexpr int Bc  = 8;
constexpr int Nc  = 8;
constexpr int HWc = 512 * 512;
constexpr int BPI = 256;              // blocks per image (1024 px per block)
constexpr float EPSc = 1e-6f;

__device__ __forceinline__ float2 gload_f2(const float* a) {
    float2 r;
    asm volatile("global_load_dwordx2 %0, %1, off" : "=v"(r) : "v"(a) : "memory");
    return r;
}
__device__ __forceinline__ int4 gload_i4(const int* a) {
    int4 r;
    asm volatile("global_load_dwordx4 %0, %1, off" : "=v"(r) : "v"(a) : "memory");
    return r;
}
#define WAITV(n_) do {                                                   \
        asm volatile("s_waitcnt vmcnt(" #n_ ")" ::: "memory");           \
        __builtin_amdgcn_sched_barrier(0);                               \
    } while (0)

__device__ __forceinline__ float wave_reduce(float v) {
#pragma unroll
    for (int off = 32; off; off >>= 1) v += __shfl_xor(v, off, 64);
    return v;
}

// 2048 blocks, 256 threads, 1024 pixels/block in two pipelined 512-px iters.
template<bool USE_PART>
__global__ __launch_bounds__(256, 4) void niou_partial(
    const float* __restrict__ pd, const float* __restrict__ gt,
    const int* __restrict__ pmask, const int* __restrict__ gmask,
    float* __restrict__ outp /* USE_PART ? part[320][BPI] : ws atomic [320][16] */)
{
    __shared__ float dnL[2][512], poL[2][512], goL[2][512];   // double buffer

    const int tid  = threadIdx.x;
    const int b    = blockIdx.x >> 8;
    const int blk  = blockIdx.x & 255;
    const int base = blk * 1024;
    const int g    = tid >> 6, q = tid & 63;

    const float* pdI = pd + (size_t)b * 4 * HWc + base;
    const float* gtI = gt + (size_t)b * 4 * HWc + base;
    const size_t mpl0 = (size_t)(b * Nc + 2 * g    ) * HWc + base + 4 * q;
    const size_t mpl1 = (size_t)(b * Nc + 2 * g + 1) * HWc + base + 4 * q;

    // ---- issue iter0: 8 rgbo dwordx2, then 8 mask int4 ----
    float2 pr0[4], gr0[4];
#pragma unroll
    for (int c = 0; c < 4; ++c) pr0[c] = gload_f2(pdI + (size_t)c * HWc + 2 * tid);
#pragma unroll
    for (int c = 0; c < 4; ++c) gr0[c] = gload_f2(gtI + (size_t)c * HWc + 2 * tid);
    int4 pmv0[2][2], gmv0[2][2];
#pragma unroll
    for (int qq = 0; qq < 2; ++qq) {
        pmv0[0][qq] = gload_i4(pmask + mpl0 + 256 * qq);
        gmv0[0][qq] = gload_i4(gmask + mpl0 + 256 * qq);
        pmv0[1][qq] = gload_i4(pmask + mpl1 + 256 * qq);
        gmv0[1][qq] = gload_i4(gmask + mpl1 + 256 * qq);
    }

    // ---- rgbo0 done (oldest 8); mask0 still in flight ----
    WAITV(8);
    {
        const float dx0 = pr0[0].x - gr0[0].x, dy0 = pr0[1].x - gr0[1].x, dz0 = pr0[2].x - gr0[2].x;
        const float dx1 = pr0[0].y - gr0[0].y, dy1 = pr0[1].y - gr0[1].y, dz1 = pr0[2].y - gr0[2].y;
        float2 d2, p2, g2;
        d2.x = sqrtf(dx0*dx0 + dy0*dy0 + dz0*dz0);
        d2.y = sqrtf(dx1*dx1 + dy1*dy1 + dz1*dz1);
        p2.x = rintf(pr0[3].x); p2.y = rintf(pr0[3].y);
        g2.x = rintf(gr0[3].x); g2.y = rintf(gr0[3].y);
        *reinterpret_cast<float2*>(&dnL[0][2 * tid]) = d2;
        *reinterpret_cast<float2*>(&poL[0][2 * tid]) = p2;
        *reinterpret_cast<float2*>(&goL[0][2 * tid]) = g2;
    }

    // ---- issue iter1: 8 rgbo, 8 masks (pipeline fill) ----
    float2 pr1[4], gr1[4];
#pragma unroll
    for (int c = 0; c < 4; ++c) pr1[c] = gload_f2(pdI + (size_t)c * HWc + 512 + 2 * tid);
#pragma unroll
    for (int c = 0; c < 4; ++c) gr1[c] = gload_f2(gtI + (size_t)c * HWc + 512 + 2 * tid);
    int4 pmv1[2][2], gmv1[2][2];
#pragma unroll
    for (int qq = 0; qq < 2; ++qq) {
        pmv1[0][qq] = gload_i4(pmask + mpl0 + 512 + 256 * qq);
        gmv1[0][qq] = gload_i4(gmask + mpl0 + 512 + 256 * qq);
        pmv1[1][qq] = gload_i4(pmask + mpl1 + 512 + 256 * qq);
        gmv1[1][qq] = gload_i4(gmask + mpl1 + 512 + 256 * qq);
    }
    __syncthreads();   // LDS buffer 0 ready

    // acc[pp]: {sim_sum, inter, gt_sum, s_sum}; count via ballot
    float acc[2][4];
    int   wcnt[2];
#pragma unroll
    for (int pp = 0; pp < 2; ++pp) {
        wcnt[pp] = 0;
#pragma unroll
        for (int k = 0; k < 4; ++k) acc[pp][k] = 0.f;
    }

#define PROCESS(pmv_, gmv_, it_)                                              \
    _Pragma("unroll")                                                         \
    for (int pp = 0; pp < 2; ++pp)                                            \
        _Pragma("unroll")                                                     \
        for (int qq = 0; qq < 2; ++qq) {                                      \
            const int li = 256 * qq + 4 * q;                                  \
            const float4 dnq = *reinterpret_cast<const float4*>(&dnL[it_][li]);\
            const float4 poq = *reinterpret_cast<const float4*>(&poL[it_][li]);\
            const float4 goq = *reinterpret_cast<const float4*>(&goL[it_][li]);\
            const int pmx[4] = {pmv_[pp][qq].x, pmv_[pp][qq].y,               \
                                pmv_[pp][qq].z, pmv_[pp][qq].w};              \
            const int gmx[4] = {gmv_[pp][qq].x, gmv_[pp][qq].y,               \
                                gmv_[pp][qq].z, gmv_[pp][qq].w};              \
            const float dnj[4] = {dnq.x, dnq.y, dnq.z, dnq.w};                \
            const float poj[4] = {poq.x, poq.y, poq.z, poq.w};                \
            const float goj[4] = {goq.x, goq.y, goq.z, goq.w};                \
            _Pragma("unroll")                                                 \
            for (int j = 0; j < 4; ++j) {                                     \
                const bool P = pmx[j] != 0;                                   \
                const bool G = gmx[j] != 0;                                   \
                wcnt[pp] += __popcll(__ballot(P));                            \
                const float s = P ? poj[j] : 0.f;                             \
                acc[pp][0] += P ? dnj[j] : 0.f;                               \
                acc[pp][1] += G ? s      : 0.f;                               \
                acc[pp][2] += G ? goj[j] : 0.f;                               \
                acc[pp][3] += s;                                              \
            }                                                                 \
        }

    // ---- iter0 masks guaranteed retired (issued 32 total, <=16 left) ----
    WAITV(16);
    PROCESS(pmv0, gmv0, 0)

    // ---- rgbo1 retired; phase1 for iter1 ----
    WAITV(8);
    {
        const float dx0 = pr1[0].x - gr1[0].x, dy0 = pr1[1].x - gr1[1].x, dz0 = pr1[2].x - gr1[2].x;
        const float dx1 = pr1[0].y - gr1[0].y, dy1 = pr1[1].y - gr1[1].y, dz1 = pr1[2].y - gr1[2].y;
        float2 d2, p2, g2;
        d2.x = sqrtf(dx0*dx0 + dy0*dy0 + dz0*dz0);
        d2.y = sqrtf(dx1*dx1 + dy1*dy1 + dz1*dz1);
        p2.x = rintf(pr1[3].x); p2.y = rintf(pr1[3].y);
        g2.x = rintf(gr1[3].x); g2.y = rintf(gr1[3].y);
        *reinterpret_cast<float2*>(&dnL[1][2 * tid]) = d2;
        *reinterpret_cast<float2*>(&poL[1][2 * tid]) = p2;
        *reinterpret_cast<float2*>(&goL[1][2 * tid]) = g2;
    }
    __syncthreads();   // LDS buffer 1 ready

    // ---- iter1 masks retired ----
    WAITV(0);
    PROCESS(pmv1, gmv1, 1)
#undef PROCESS

    // ---- wave-level reduction; lane0 stores 10 partials (no atomics) ----
    const int lane = tid & 63;
#pragma unroll
    for (int pp = 0; pp < 2; ++pp) {
        const float s0 = wave_reduce(acc[pp][0]);
        const float s1 = wave_reduce(acc[pp][1]);
        const float s2 = wave_reduce(acc[pp][2]);
        const float s3 = wave_reduce(acc[pp][3]);
        if (lane == 0) {
            const int n = 2 * g + pp;
            if (USE_PART) {
                float* dst = outp + (size_t)(b * 40 + n * 5) * BPI + blk;
                dst[0 * BPI] = s0;
                dst[1 * BPI] = (float)wcnt[pp];
                dst[2 * BPI] = s1;
                dst[3 * BPI] = s2;
                dst[4 * BPI] = s3;
            } else {   // fallback: 20KB atomic layout (PAD=16)
                float* wsn = outp + (size_t)(b * 40 + n * 5) * 16;
                atomicAdd(&wsn[0 * 16], s0);
                atomicAdd(&wsn[1 * 16], (float)wcnt[pp]);
                atomicAdd(&wsn[2 * 16], s1);
                atomicAdd(&wsn[3 * 16], s2);
                atomicAdd(&wsn[4 * 16], s3);
            }
        }
    }
}

// 320 blocks x 256 threads: sums[slot] = sum of BPI per-block partials.
__global__ __launch_bounds__(256) void niou_reduce(
    const float* __restrict__ part, float* __restrict__ sums)
{
    const int slot = blockIdx.x;     // 0..319
    const int tid  = threadIdx.x;
    float s = 0.f;
#pragma unroll
    for (int i = 0; i < BPI; i += 256)
        if (i + tid < BPI) s += part[(size_t)slot * BPI + i + tid];
    s = wave_reduce(s);
    __shared__ float w4[4];
    if ((tid & 63) == 0) w4[tid >> 6] = s;
    __syncthreads();
    if (tid == 0) sums[slot] = w4[0] + w4[1] + w4[2] + w4[3];
}

__global__ __launch_bounds__(64) void niou_final(
    const float* __restrict__ w0, float* __restrict__ out, int pad)
{
    const int t = threadIdx.x;   // 0..63 == b*8+n
    const float* w = w0 + (size_t)t * 5 * pad;
    const float sim   = w[0 * pad];
    const float cnt   = w[1 * pad];
    const float inter = w[2 * pad];
    const float gts   = w[3 * pad];
    const float ssum  = w[4 * pad];
    const float xo    = ssum - inter;            // pd_xor_sum
    const float punish = sim / (cnt + EPSc);
    const float iou    = inter / (gts + xo + EPSc);
    float term = 1.0f - iou + punish;
#pragma unroll
    for (int off = 32; off; off >>= 1) term += __shfl_xor(term, off, 64);
    if (t == 0) out[0] = term * (1.0f / 64.0f);
}

extern "C" void kernel_launch(void* const* d_in, const int* in_sizes, int n_in,
                              void* d_out, int out_size, void* d_ws, size_t ws_size,
                              hipStream_t stream) {
    const float* pd_rgbo = (const float*)d_in[0];
    const float* gt_rgbo = (const float*)d_in[1];
    const int*   pd_mask = (const int*)d_in[2];
    const int*   gt_mask = (const int*)d_in[3];
    float* out = (float*)d_out;
    float* ws  = (float*)d_ws;

    const size_t need = ((size_t)320 * BPI + 320) * sizeof(float);
    if (ws_size >= need) {
        float* part = ws;
        float* sums = ws + (size_t)320 * BPI;
        niou_partial<true><<<Bc * BPI, 256, 0, stream>>>(pd_rgbo, gt_rgbo,
                                                         pd_mask, gt_mask, part);
        niou_reduce<<<320, 256, 0, stream>>>(part, sums);
        niou_final<<<1, 64, 0, stream>>>(sums, out, 1);
    } else {
        hipMemsetAsync(ws, 0, 320 * 16 * sizeof(float), stream);
        niou_partial<false><<<Bc * BPI, 256, 0, stream>>>(pd_rgbo, gt_rgbo,
                                                          pd_mask, gt_mask, ws);
        niou_final<<<1, 64, 0, stream>>>(ws, out, 16);
    }
}